// Round 1
// baseline (1213.777 us; speedup 1.0000x reference)
//
#include <hip/hip_runtime.h>

// Problem constants (B=1)
#define T_    8
#define C_    64
#define H_    256
#define W_    256
#define HD_   4
#define CH_   16     // C_/HD_
#define PS_   7
#define Q_    32768
#define KTOT_ 15
#define K_    10
#define HW_   (H_*W_)

// ---------------------------------------------------------------------------
// Kernel 1: transpose vid [T][C][H][W] -> vidT [T][H][W][C]  (channels-last)
// Block: 256 threads handles one (t, h, 64-wide w tile). LDS 64x65 f32 tile.
// ---------------------------------------------------------------------------
__global__ __launch_bounds__(256) void transpose_vid_kernel(
    const float* __restrict__ vid, float* __restrict__ vidT) {
  __shared__ float tile[64][65];   // +1 pad: conflict-free both directions
  const int b  = blockIdx.x;       // grid = T_*H_*(W_/64) = 8192
  const int wt = b & 3;
  const int h  = (b >> 2) & (H_ - 1);
  const int t  = b >> 10;
  const int w0 = wt * 64;

  // Load: 64 channels x 64 w, coalesced along w (float4 per thread).
  const float* src = vid + (size_t)t * C_ * HW_ + (size_t)h * W_ + w0;
  const int wq = (threadIdx.x & 15) * 4;   // 0,4,...,60
  const int c0 = threadIdx.x >> 4;         // 0..15
  #pragma unroll
  for (int i = 0; i < 4; ++i) {
    const int c = c0 + i * 16;
    const float4 v = *reinterpret_cast<const float4*>(src + (size_t)c * HW_ + wq);
    tile[c][wq + 0] = v.x; tile[c][wq + 1] = v.y;
    tile[c][wq + 2] = v.z; tile[c][wq + 3] = v.w;
  }
  __syncthreads();

  // Store: coalesced along c (float4 per thread).
  float* dst = vidT + (((size_t)t * H_ + h) * W_ + w0) * C_;
  const int cq = (threadIdx.x & 15) * 4;   // 0,4,...,60
  const int w1 = threadIdx.x >> 4;         // 0..15
  #pragma unroll
  for (int i = 0; i < 4; ++i) {
    const int w = w1 + i * 16;
    float4 v;
    v.x = tile[cq + 0][w]; v.y = tile[cq + 1][w];
    v.z = tile[cq + 2][w]; v.w = tile[cq + 3][w];
    *reinterpret_cast<float4*>(dst + (size_t)w * C_ + cq) = v;
  }
}

// ---------------------------------------------------------------------------
// Kernel 2: weighted patch-sum gather.
// Block = 448 threads (7 waves) handles one q. Wave w owns patch row pi=w
// (7 pj positions). lane = hd*16 + c so that:
//   TR path : per (k,pos) wave-load touches 4 fully-used 64B lines
//   output  : 256B fully-coalesced wave stores (matches out layout exactly)
// out[(q*49 + pi*7 + pj)*64 + hd*16 + c] =
//   sum_k dists[hd][q][k] * vid[t_k][hd*16+c][hi_k+pi][wi_k+pj]
// ---------------------------------------------------------------------------
template <bool TR>
__global__ __launch_bounds__(448) void wpsum_kernel(
    const float* __restrict__ vsrc,     // vidT (TR) or vid (!TR)
    const float* __restrict__ dists,
    const int*   __restrict__ inds,
    float*       __restrict__ out) {
  const int q   = blockIdx.x;
  const int tid = threadIdx.x;

  __shared__ int   s_off[HD_][K_];
  __shared__ float s_w[HD_][K_];
  if (tid < HD_ * K_) {
    const int hd = tid / K_, k = tid % K_;
    const int* ip = inds + (((size_t)hd * Q_ + q) * KTOT_ + k) * 3;
    const int t = ip[0], hi = ip[1], wi = ip[2];
    if (TR)
      s_off[hd][k] = ((t * H_ + hi) * W_ + wi) * C_ + hd * CH_;
    else
      s_off[hd][k] = ((t * C_ + hd * CH_) * H_ + hi) * W_ + wi;
    s_w[hd][k] = dists[((size_t)hd * Q_ + q) * KTOT_ + k];
  }
  __syncthreads();

  const int lane = tid & 63;
  const int wave = tid >> 6;          // 0..6 == patch row pi
  const int hd   = lane >> 4;
  const int c    = lane & 15;

  float wk[K_];
  int   off[K_];
  #pragma unroll
  for (int k = 0; k < K_; ++k) {
    wk[k]  = s_w[hd][k];
    off[k] = s_off[hd][k] + (TR ? c : c * HW_);
  }

  const int pi = wave;
  #pragma unroll
  for (int pj = 0; pj < PS_; ++pj) {
    const int d = TR ? ((pi * W_ + pj) * C_) : (pi * W_ + pj);
    float acc = 0.f;
    #pragma unroll
    for (int k = 0; k < K_; ++k)
      acc = fmaf(wk[k], vsrc[(size_t)(off[k] + d)], acc);
    out[((size_t)q * (PS_ * PS_) + pi * PS_ + pj) * (HD_ * CH_) + lane] = acc;
  }
}

// ---------------------------------------------------------------------------
extern "C" void kernel_launch(void* const* d_in, const int* in_sizes, int n_in,
                              void* d_out, int out_size, void* d_ws, size_t ws_size,
                              hipStream_t stream) {
  const float* vid   = (const float*)d_in[0];
  const float* dists = (const float*)d_in[1];
  const int*   inds  = (const int*)d_in[2];
  float*       out   = (float*)d_out;

  const size_t need = (size_t)T_ * C_ * HW_ * sizeof(float);  // 128 MiB
  if (ws_size >= need) {
    float* vidT = (float*)d_ws;
    transpose_vid_kernel<<<T_ * H_ * (W_ / 64), 256, 0, stream>>>(vid, vidT);
    wpsum_kernel<true><<<Q_, 448, 0, stream>>>(vidT, dists, inds, out);
  } else {
    // Fallback: gather directly from native layout (correct, slower).
    wpsum_kernel<false><<<Q_, 448, 0, stream>>>(vid, dists, inds, out);
  }
}